// Round 1
// baseline (165.418 us; speedup 1.0000x reference)
//
#include <hip/hip_runtime.h>
#include <hip/hip_bf16.h>

#define N_BCH 8
#define N_ATM 10000
#define N_ELM 100

typedef int   i4 __attribute__((ext_vector_type(4)));
typedef float f4 __attribute__((ext_vector_type(4)));

__global__ void zero_out_kernel(float* __restrict__ out) {
    if (threadIdx.x < N_BCH) out[threadIdx.x] = 0.0f;
}

__launch_bounds__(256)
__global__ void edge_kernel(const int* __restrict__ elm,
                            const int* __restrict__ edge_n,
                            const int* __restrict__ edge_i,
                            const int* __restrict__ edge_j,
                            const float* __restrict__ sod,
                            const float* __restrict__ kparam,
                            const float* __restrict__ radius,
                            float* __restrict__ out,
                            int nE) {
    float acc[N_BCH];
#pragma unroll
    for (int b = 0; b < N_BCH; ++b) acc[b] = 0.0f;

    const int tid    = blockIdx.x * blockDim.x + threadIdx.x;
    const int stride = gridDim.x * blockDim.x;
    const int nvec   = nE >> 2;

    const i4* en4 = (const i4*)edge_n;
    const i4* ei4 = (const i4*)edge_i;
    const i4* ej4 = (const i4*)edge_j;
    const f4* s4  = (const f4*)sod;

    for (int v = tid; v < nvec; v += stride) {
        i4 nn = __builtin_nontemporal_load(en4 + v);
        i4 ii = __builtin_nontemporal_load(ei4 + v);
        i4 jj = __builtin_nontemporal_load(ej4 + v);
        f4 ss = __builtin_nontemporal_load(s4  + v);

#pragma unroll
        for (int u = 0; u < 4; ++u) {
            int   n  = nn[u];
            int   ei = elm[n * N_ATM + ii[u]];
            int   ej = elm[n * N_ATM + jj[u]];
            float dis = sqrtf(ss[u]);
            float kk = kparam[ei] + kparam[ej];
            float R  = radius[ei] + radius[ej];
            float d  = dis - R;
            float val = (dis < R) ? kk * d * d : 0.0f;
#pragma unroll
            for (int b = 0; b < N_BCH; ++b)
                acc[b] += (n == b) ? val : 0.0f;
        }
    }

    // scalar tail (nE % 4), handled by the first few global threads
    const int tail_start = nvec << 2;
    const int tail_n = nE - tail_start;
    if (tid < tail_n) {
        int e = tail_start + tid;
        int   n  = edge_n[e];
        int   ei = elm[n * N_ATM + edge_i[e]];
        int   ej = elm[n * N_ATM + edge_j[e]];
        float dis = sqrtf(sod[e]);
        float kk = kparam[ei] + kparam[ej];
        float R  = radius[ei] + radius[ej];
        float d  = dis - R;
        float val = (dis < R) ? kk * d * d : 0.0f;
#pragma unroll
        for (int b = 0; b < N_BCH; ++b)
            acc[b] += (n == b) ? val : 0.0f;
    }

    // wave(64) shuffle reduction for each bin
#pragma unroll
    for (int b = 0; b < N_BCH; ++b) {
        float v = acc[b];
#pragma unroll
        for (int off = 32; off > 0; off >>= 1)
            v += __shfl_down(v, off, 64);
        acc[b] = v;
    }

    __shared__ float smem[4][N_BCH];  // 256 threads = 4 waves
    const int wave = threadIdx.x >> 6;
    const int lane = threadIdx.x & 63;
    if (lane == 0) {
#pragma unroll
        for (int b = 0; b < N_BCH; ++b) smem[wave][b] = acc[b];
    }
    __syncthreads();
    if (threadIdx.x < N_BCH) {
        float v = smem[0][threadIdx.x] + smem[1][threadIdx.x] +
                  smem[2][threadIdx.x] + smem[3][threadIdx.x];
        atomicAdd(&out[threadIdx.x], v);
    }
}

extern "C" void kernel_launch(void* const* d_in, const int* in_sizes, int n_in,
                              void* d_out, int out_size, void* d_ws, size_t ws_size,
                              hipStream_t stream) {
    const int*   elm    = (const int*)d_in[0];
    const int*   edge_n = (const int*)d_in[1];
    const int*   edge_i = (const int*)d_in[2];
    const int*   edge_j = (const int*)d_in[3];
    const float* sod    = (const float*)d_in[4];
    const float* kparam = (const float*)d_in[5];
    const float* radius = (const float*)d_in[6];
    float* out = (float*)d_out;
    const int nE = in_sizes[1];

    hipLaunchKernelGGL(zero_out_kernel, dim3(1), dim3(64), 0, stream, out);
    hipLaunchKernelGGL(edge_kernel, dim3(1024), dim3(256), 0, stream,
                       elm, edge_n, edge_i, edge_j, sod, kparam, radius, out, nE);
}